// Round 3
// baseline (842.045 us; speedup 1.0000x reference)
//
#include <hip/hip_runtime.h>

#define DD 128

typedef __attribute__((ext_vector_type(8))) short short8;
typedef __attribute__((ext_vector_type(4))) float f32x4;
typedef __attribute__((ext_vector_type(2))) float f32x2;

__device__ __forceinline__ unsigned short f2bf(float f) {
    union { float f; unsigned int i; } c; c.f = f;
    unsigned int x = c.i;
    return (unsigned short)((x + 0x7fffu + ((x >> 16) & 1u)) >> 16);
}
// Index accessor robust to int32 vs int64 (little-endian, nonneg values < 2^31)
__device__ __forceinline__ int idx_at(const int* p, int e, int is64) {
    return is64 ? p[2 * e] : p[e];
}

// ---- detect int64 indices: int64 => all odd 32-bit words (high halves) zero.
__global__ __launch_bounds__(256) void detect_k(const int* dst, int nE, int* nz) {
    int t = blockIdx.x * 256 + threadIdx.x;
    int w = 2 * t + 1;
    if (w < nE && dst[w] != 0) atomicOr(nz, 1);
}

// ---- in-degree histogram
__global__ __launch_bounds__(256) void hist_k(const int* dst, int nE, const int* nz,
                                              int* deg) {
    int e = blockIdx.x * 256 + threadIdx.x;
    if (e >= nE) return;
    int is64 = (*nz == 0);
    atomicAdd(deg + idx_at(dst, e, is64), 1);
}

// ---- transpose + fp32->bf16 convert the four 128x128 weights: Wt[n*128+k]=W[k*128+n]
__global__ __launch_bounds__(256) void transw_k(
    const float* __restrict__ W0, const float* __restrict__ W1,
    const float* __restrict__ W2, const float* __restrict__ W3,
    unsigned short* __restrict__ Wt) {
    const float* Ws[4] = {W0, W1, W2, W3};
    int w = blockIdx.x >> 4;
    int chunk = blockIdx.x & 15;
    const float* W = Ws[w];
    unsigned short* T = Wt + w * (DD * DD);
    #pragma unroll
    for (int i = 0; i < 4; ++i) {
        int t = chunk * 1024 + i * 256 + threadIdx.x;
        int n = t >> 7, k = t & 127;
        T[t] = f2bf(W[k * DD + n]);
    }
}

// ---- edge scatter: agg[dst] += h[src] + emb[etype] (fp32 atomics into d_out).
// One wave per edge; lane covers 2 columns.
__global__ __launch_bounds__(256) void scatter_k(
    const float* __restrict__ h, const float* __restrict__ emb,
    const int* __restrict__ src, const int* __restrict__ dst,
    const int* __restrict__ et, const int* __restrict__ nz,
    float* agg, int nE) {
    int lane = threadIdx.x & 63;
    int e = blockIdx.x * 4 + (threadIdx.x >> 6);
    if (e >= nE) return;
    int is64 = (*nz == 0);
    int s = idx_at(src, e, is64), d = idx_at(dst, e, is64), r = idx_at(et, e, is64);
    f32x2 hv = *(const f32x2*)(h + (size_t)s * DD + lane * 2);
    f32x2 rv = *(const f32x2*)(emb + (size_t)r * DD + lane * 2);
    float* ap = agg + (size_t)d * DD + lane * 2;
    unsafeAtomicAdd(ap, hv.x + rv.x);
    unsafeAtomicAdd(ap + 1, hv.y + rv.y);
}

// ---- fused 4-GEMM + epilogue. Block = 4 waves, 64 nodes/block, wave w -> cols
// [32w,32w+32). agg aliases out (same rows only; __syncthreads between read/write).
__global__ __launch_bounds__(256, 2) void fused_k(
    const float* __restrict__ h, const float* __restrict__ prevh,
    const float* __restrict__ normv, const float* __restrict__ bias,
    const float* agg,                    // = d_out (fp32 aggregate)
    const int* __restrict__ deg, const unsigned short* __restrict__ Wt,
    float* out, int nN) {
    const int lane = threadIdx.x & 63;
    const int wv = threadIdx.x >> 6;
    const int q = lane >> 4, cl = lane & 15;
    const int node_base = blockIdx.x * 64;
    const int ncb = wv * 32;

    f32x4 acc[4][4][2];
    #pragma unroll
    for (int g = 0; g < 4; ++g)
        #pragma unroll
        for (int mt = 0; mt < 4; ++mt)
            #pragma unroll
            for (int nt = 0; nt < 2; ++nt)
                acc[g][mt][nt] = (f32x4){0.f, 0.f, 0.f, 0.f};

    #pragma unroll
    for (int g = 0; g < 4; ++g) {
        const float* Ap = (g == 0) ? agg : ((g == 3) ? prevh : h);
        const unsigned short* Wg = Wt + g * (DD * DD);
        short8 bfr[2][4];
        #pragma unroll
        for (int nt = 0; nt < 2; ++nt) {
            int n = ncb + nt * 16 + cl;
            #pragma unroll
            for (int ks = 0; ks < 4; ++ks)
                bfr[nt][ks] = *(const short8*)(Wg + n * DD + ks * 32 + q * 8);
        }
        #pragma unroll
        for (int mt = 0; mt < 4; ++mt) {
            int row = node_base + mt * 16 + cl;
            if (row > nN - 1) row = nN - 1;   // clamp stays within this block's rows
            #pragma unroll
            for (int ks = 0; ks < 4; ++ks) {
                const float* ap = Ap + (size_t)row * DD + ks * 32 + q * 8;
                f32x4 x0 = *(const f32x4*)ap;
                f32x4 x1 = *(const f32x4*)(ap + 4);
                short8 a;
                #pragma unroll
                for (int j = 0; j < 4; ++j) {
                    a[j]     = (short)f2bf(x0[j]);
                    a[4 + j] = (short)f2bf(x1[j]);
                }
                #pragma unroll
                for (int nt = 0; nt < 2; ++nt)
                    acc[g][mt][nt] = __builtin_amdgcn_mfma_f32_16x16x32_bf16(
                        a, bfr[nt][ks], acc[g][mt][nt], 0, 0, 0);
            }
        }
    }

    __syncthreads();   // all agg (=out) reads done before any epilogue write

    // C/D layout: col = lane&15, row = quad*4 + reg
    #pragma unroll
    for (int mt = 0; mt < 4; ++mt) {
        #pragma unroll
        for (int r = 0; r < 4; ++r) {
            int node = node_base + mt * 16 + q * 4 + r;
            if (node >= nN) continue;
            float nm = normv[node];
            int dg = deg[node];
            #pragma unroll
            for (int nt = 0; nt < 2; ++nt) {
                int col = ncb + nt * 16 + cl;
                float aggv = acc[0][mt][nt][r] * nm;
                float lv   = (dg > 0) ? acc[1][mt][nt][r] : acc[2][mt][nt][r];
                float pre  = acc[3][mt][nt][r] + bias[col];
                float sg   = 1.0f / (1.0f + __expf(-pre));
                float pv   = prevh[(size_t)node * DD + col];
                float o    = sg * (aggv + lv) + (1.0f - sg) * pv;
                out[(size_t)node * DD + col] = (o > 0.f ? o : 0.f);
            }
        }
    }
}

extern "C" void kernel_launch(void* const* d_in, const int* in_sizes, int n_in,
                              void* d_out, int out_size, void* d_ws, size_t ws_size,
                              hipStream_t stream) {
    const float* h     = (const float*)d_in[0];
    const float* prevh = (const float*)d_in[1];
    const float* emb   = (const float*)d_in[2];
    const float* normv = (const float*)d_in[3];
    const float* Wn    = (const float*)d_in[4];
    const float* Wl    = (const float*)d_in[5];
    const float* We    = (const float*)d_in[6];
    const float* Wsk   = (const float*)d_in[7];
    const float* bias  = (const float*)d_in[8];
    const int* src   = (const int*)d_in[9];
    const int* dst   = (const int*)d_in[10];
    const int* etype = (const int*)d_in[11];

    int nN = in_sizes[3];   // norm is [N,1]
    int nE = in_sizes[9];

    // ws layout: Wt (4*128*128 bf16 = 128 KiB), then deg[N], nz[1]  => ~530 KB
    unsigned short* Wt = (unsigned short*)d_ws;
    int* deg = (int*)((char*)d_ws + 4 * DD * DD * sizeof(unsigned short));
    int* nz  = deg + nN;

    float* agg = (float*)d_out;   // fp32 [N,128] aggregate lives in d_out

    hipMemsetAsync(d_out, 0, (size_t)nN * DD * sizeof(float), stream);
    hipMemsetAsync(deg, 0, (size_t)(nN + 1) * sizeof(int), stream);  // deg + nz

    detect_k<<<(nE / 2 + 255) / 256, 256, 0, stream>>>(dst, nE, nz);
    hist_k<<<(nE + 255) / 256, 256, 0, stream>>>(dst, nE, nz, deg);
    transw_k<<<64, 256, 0, stream>>>(Wn, Wl, We, Wsk, Wt);
    scatter_k<<<(nE + 3) / 4, 256, 0, stream>>>(h, emb, src, dst, etype, nz, agg, nE);
    fused_k<<<(nN + 63) / 64, 256, 0, stream>>>(h, prevh, normv, bias, agg, deg, Wt,
                                                (float*)d_out, nN);
    (void)ws_size; (void)n_in; (void)out_size;
}

// Round 4
// 461.612 us; speedup vs baseline: 1.8241x; 1.8241x over previous
//
#include <hip/hip_runtime.h>

#define DD 128

typedef __attribute__((ext_vector_type(8))) short short8;
typedef __attribute__((ext_vector_type(4))) float f32x4;
typedef __attribute__((ext_vector_type(2))) float f32x2;

__device__ __forceinline__ unsigned short f2bf(float f) {
    union { float f; unsigned int i; } c; c.f = f;
    unsigned int x = c.i;
    return (unsigned short)((x + 0x7fffu + ((x >> 16) & 1u)) >> 16);
}
// Index accessor robust to int32 vs int64 (little-endian, nonneg values < 2^31)
__device__ __forceinline__ int idx_at(const int* p, int e, int is64) {
    return is64 ? p[2 * e] : p[e];
}

// ---- detect int64 indices: int64 => all odd 32-bit words (high halves) zero.
__global__ __launch_bounds__(256) void detect_k(const int* dst, int nE, int* nz) {
    int t = blockIdx.x * 256 + threadIdx.x;
    int w = 2 * t + 1;
    if (w < nE && dst[w] != 0) atomicOr(nz, 1);
}

// ---- in-degree histogram
__global__ __launch_bounds__(256) void hist_k(const int* dst, int nE, const int* nz,
                                              int* deg) {
    int e = blockIdx.x * 256 + threadIdx.x;
    if (e >= nE) return;
    int is64 = (*nz == 0);
    atomicAdd(deg + idx_at(dst, e, is64), 1);
}

// ---- exclusive scan, step 1: per-1024-block scan
__global__ __launch_bounds__(1024) void scan1_k(const int* deg, int* off, int* bsum,
                                                int nN) {
    __shared__ int s[1024];
    int t = threadIdx.x, i = blockIdx.x * 1024 + t;
    int v = (i < nN) ? deg[i] : 0;
    s[t] = v;
    __syncthreads();
    for (int d = 1; d < 1024; d <<= 1) {
        int x = (t >= d) ? s[t - d] : 0;
        __syncthreads();
        s[t] += x;
        __syncthreads();
    }
    if (i < nN) off[i] = s[t] - v;          // exclusive
    if (t == 1023) bsum[blockIdx.x] = s[1023];
}

// ---- step 2: scan block sums (nB <= 1024)
__global__ __launch_bounds__(1024) void scan2_k(int* bsum, int nB) {
    __shared__ int s[1024];
    int t = threadIdx.x;
    int v = (t < nB) ? bsum[t] : 0;
    s[t] = v;
    __syncthreads();
    for (int d = 1; d < 1024; d <<= 1) {
        int x = (t >= d) ? s[t - d] : 0;
        __syncthreads();
        s[t] += x;
        __syncthreads();
    }
    if (t < nB) bsum[t] = s[t] - v;         // exclusive
}

// ---- step 3: add block offsets; init cursor = off
__global__ __launch_bounds__(1024) void scan3_k(int* off, const int* bsum, int* cursor,
                                                int nN) {
    int i = blockIdx.x * 1024 + threadIdx.x;
    if (i >= nN) return;
    int o = off[i] + bsum[blockIdx.x];
    off[i] = o;
    cursor[i] = o;
}

// ---- counting sort: edges_sorted[pos] = (src, etype), bucketed by dst
__global__ __launch_bounds__(256) void sort_k(const int* src, const int* dst,
                                              const int* et, int nE, const int* nz,
                                              int* cursor, int2* edges) {
    int e = blockIdx.x * 256 + threadIdx.x;
    if (e >= nE) return;
    int is64 = (*nz == 0);
    int d = idx_at(dst, e, is64);
    int pos = atomicAdd(cursor + d, 1);
    edges[pos] = make_int2(idx_at(src, e, is64), idx_at(et, e, is64));
}

// ---- transpose + fp32->bf16 convert the four 128x128 weights: Wt[n*128+k]=W[k*128+n]
__global__ __launch_bounds__(256) void transw_k(
    const float* __restrict__ W0, const float* __restrict__ W1,
    const float* __restrict__ W2, const float* __restrict__ W3,
    unsigned short* __restrict__ Wt) {
    const float* Ws[4] = {W0, W1, W2, W3};
    int w = blockIdx.x >> 4;
    int chunk = blockIdx.x & 15;
    const float* W = Ws[w];
    unsigned short* T = Wt + w * (DD * DD);
    #pragma unroll
    for (int i = 0; i < 4; ++i) {
        int t = chunk * 1024 + i * 256 + threadIdx.x;
        int n = t >> 7, k = t & 127;
        T[t] = f2bf(W[k * DD + n]);
    }
}

// ---- CSR gather: agg[v] = sum over incoming edges of (h[src] + emb[etype]).
// One wave per node, fp32 register accumulate, single write per row.
__global__ __launch_bounds__(256) void gather_k(
    const float* __restrict__ h, const float* __restrict__ emb,
    const int2* __restrict__ edges, const int* __restrict__ off,
    const int* __restrict__ deg, float* __restrict__ agg, int nN) {
    int lane = threadIdx.x & 63;
    int v = blockIdx.x * 4 + (threadIdx.x >> 6);
    if (v >= nN) return;
    int b = off[v], n = deg[v];
    float a0 = 0.f, a1 = 0.f;
    int i = 0;
    for (; i + 2 <= n; i += 2) {          // 2-way unroll for MLP
        int2 e0 = edges[b + i];
        int2 e1 = edges[b + i + 1];
        f32x2 h0 = *(const f32x2*)(h + (size_t)e0.x * DD + lane * 2);
        f32x2 r0 = *(const f32x2*)(emb + (size_t)e0.y * DD + lane * 2);
        f32x2 h1 = *(const f32x2*)(h + (size_t)e1.x * DD + lane * 2);
        f32x2 r1 = *(const f32x2*)(emb + (size_t)e1.y * DD + lane * 2);
        a0 += (h0.x + r0.x) + (h1.x + r1.x);
        a1 += (h0.y + r0.y) + (h1.y + r1.y);
    }
    if (i < n) {
        int2 e0 = edges[b + i];
        f32x2 h0 = *(const f32x2*)(h + (size_t)e0.x * DD + lane * 2);
        f32x2 r0 = *(const f32x2*)(emb + (size_t)e0.y * DD + lane * 2);
        a0 += h0.x + r0.x;
        a1 += h0.y + r0.y;
    }
    *(f32x2*)(agg + (size_t)v * DD + lane * 2) = (f32x2){a0, a1};
}

// ---- fused 4-GEMM + epilogue. Block = 4 waves, 64 nodes/block, wave w -> cols
// [32w,32w+32). agg aliases out (same rows only; __syncthreads between read/write).
__global__ __launch_bounds__(256, 2) void fused_k(
    const float* __restrict__ h, const float* __restrict__ prevh,
    const float* __restrict__ normv, const float* __restrict__ bias,
    const float* agg,                    // = d_out (fp32 aggregate)
    const int* __restrict__ deg, const unsigned short* __restrict__ Wt,
    float* out, int nN) {
    const int lane = threadIdx.x & 63;
    const int wv = threadIdx.x >> 6;
    const int q = lane >> 4, cl = lane & 15;
    const int node_base = blockIdx.x * 64;
    const int ncb = wv * 32;

    f32x4 acc[4][4][2];
    #pragma unroll
    for (int g = 0; g < 4; ++g)
        #pragma unroll
        for (int mt = 0; mt < 4; ++mt)
            #pragma unroll
            for (int nt = 0; nt < 2; ++nt)
                acc[g][mt][nt] = (f32x4){0.f, 0.f, 0.f, 0.f};

    #pragma unroll
    for (int g = 0; g < 4; ++g) {
        const float* Ap = (g == 0) ? agg : ((g == 3) ? prevh : h);
        const unsigned short* Wg = Wt + g * (DD * DD);
        short8 bfr[2][4];
        #pragma unroll
        for (int nt = 0; nt < 2; ++nt) {
            int n = ncb + nt * 16 + cl;
            #pragma unroll
            for (int ks = 0; ks < 4; ++ks)
                bfr[nt][ks] = *(const short8*)(Wg + n * DD + ks * 32 + q * 8);
        }
        #pragma unroll
        for (int mt = 0; mt < 4; ++mt) {
            int row = node_base + mt * 16 + cl;
            if (row > nN - 1) row = nN - 1;   // clamp stays within this block's rows
            #pragma unroll
            for (int ks = 0; ks < 4; ++ks) {
                const float* ap = Ap + (size_t)row * DD + ks * 32 + q * 8;
                f32x4 x0 = *(const f32x4*)ap;
                f32x4 x1 = *(const f32x4*)(ap + 4);
                short8 a;
                #pragma unroll
                for (int j = 0; j < 4; ++j) {
                    a[j]     = (short)f2bf(x0[j]);
                    a[4 + j] = (short)f2bf(x1[j]);
                }
                #pragma unroll
                for (int nt = 0; nt < 2; ++nt)
                    acc[g][mt][nt] = __builtin_amdgcn_mfma_f32_16x16x32_bf16(
                        a, bfr[nt][ks], acc[g][mt][nt], 0, 0, 0);
            }
        }
    }

    __syncthreads();   // all agg (=out) reads done before any epilogue write

    // C/D layout: col = lane&15, row = quad*4 + reg
    #pragma unroll
    for (int mt = 0; mt < 4; ++mt) {
        #pragma unroll
        for (int r = 0; r < 4; ++r) {
            int node = node_base + mt * 16 + q * 4 + r;
            if (node >= nN) continue;
            float nm = normv[node];
            int dg = deg[node];
            #pragma unroll
            for (int nt = 0; nt < 2; ++nt) {
                int col = ncb + nt * 16 + cl;
                float aggv = acc[0][mt][nt][r] * nm;
                float lv   = (dg > 0) ? acc[1][mt][nt][r] : acc[2][mt][nt][r];
                float pre  = acc[3][mt][nt][r] + bias[col];
                float sg   = 1.0f / (1.0f + __expf(-pre));
                float pv   = prevh[(size_t)node * DD + col];
                float o    = sg * (aggv + lv) + (1.0f - sg) * pv;
                out[(size_t)node * DD + col] = (o > 0.f ? o : 0.f);
            }
        }
    }
}

extern "C" void kernel_launch(void* const* d_in, const int* in_sizes, int n_in,
                              void* d_out, int out_size, void* d_ws, size_t ws_size,
                              hipStream_t stream) {
    const float* h     = (const float*)d_in[0];
    const float* prevh = (const float*)d_in[1];
    const float* emb   = (const float*)d_in[2];
    const float* normv = (const float*)d_in[3];
    const float* Wn    = (const float*)d_in[4];
    const float* Wl    = (const float*)d_in[5];
    const float* We    = (const float*)d_in[6];
    const float* Wsk   = (const float*)d_in[7];
    const float* bias  = (const float*)d_in[8];
    const int* src   = (const int*)d_in[9];
    const int* dst   = (const int*)d_in[10];
    const int* etype = (const int*)d_in[11];

    int nN = in_sizes[3];   // norm is [N,1]
    int nE = in_sizes[9];

    // ws layout: Wt 128KB | deg[N] nz[1] off[N] cursor[N] bsum[1024] | edges[E] int2
    // total ~5.6 MB
    unsigned short* Wt = (unsigned short*)d_ws;
    int* ibase  = (int*)((char*)d_ws + 4 * DD * DD * sizeof(unsigned short));
    int* deg    = ibase;
    int* nz     = deg + nN;
    int* off    = nz + 1;
    int* cursor = off + nN;
    int* bsum   = cursor + nN;
    int2* edges = (int2*)(bsum + 1024);

    float* agg = (float*)d_out;   // fp32 [N,128] aggregate lives in d_out

    hipMemsetAsync(deg, 0, (size_t)(nN + 1) * sizeof(int), stream);  // deg + nz

    int nB = (nN + 1023) / 1024;
    detect_k<<<(nE / 2 + 255) / 256, 256, 0, stream>>>(dst, nE, nz);
    hist_k<<<(nE + 255) / 256, 256, 0, stream>>>(dst, nE, nz, deg);
    scan1_k<<<nB, 1024, 0, stream>>>(deg, off, bsum, nN);
    scan2_k<<<1, 1024, 0, stream>>>(bsum, nB);
    scan3_k<<<nB, 1024, 0, stream>>>(off, bsum, cursor, nN);
    sort_k<<<(nE + 255) / 256, 256, 0, stream>>>(src, dst, etype, nE, nz, cursor, edges);
    transw_k<<<64, 256, 0, stream>>>(Wn, Wl, We, Wsk, Wt);
    gather_k<<<(nN + 3) / 4, 256, 0, stream>>>(h, emb, edges, off, deg, agg, nN);
    fused_k<<<(nN + 63) / 64, 256, 0, stream>>>(h, prevh, normv, bias, agg, deg, Wt,
                                                (float*)d_out, nN);
    (void)ws_size; (void)n_in; (void)out_size;
}